// Round 9
// baseline (171.306 us; speedup 1.0000x reference)
//
#include <hip/hip_runtime.h>

typedef __attribute__((ext_vector_type(8))) short bf16x8;
typedef __attribute__((ext_vector_type(4))) float f32x4;
typedef __attribute__((ext_vector_type(16))) float f32x16;
typedef __attribute__((ext_vector_type(8))) unsigned short u16x8;
typedef __attribute__((ext_vector_type(4))) unsigned int u32x4;

#define TT 2048

__device__ __forceinline__ unsigned short f2bf(float f) {
  unsigned int u = __builtin_bit_cast(unsigned int, f);
  u += 0x7FFFu + ((u >> 16) & 1u);
  return (unsigned short)(u >> 16);
}

__device__ __forceinline__ void gld16(const void* g, void* l) {
  __builtin_amdgcn_global_load_lds((const __attribute__((address_space(1))) void*)g,
                                   (__attribute__((address_space(3))) void*)l, 16, 0, 0);
}

__device__ __forceinline__ unsigned int cvtpk(float lo, float hi) {
  unsigned int r;
  asm("v_cvt_pk_bf16_f32 %0, %1, %2" : "=v"(r) : "v"(lo), "v"(hi));
  return r;
}

__device__ __forceinline__ void pl32swap(unsigned int& a, unsigned int& b) {
  asm volatile("v_permlane32_swap_b32 %0, %1" : "+v"(a), "+v"(b));
}

// ---- fused input conversion:
// blocks [0,4096): x (fp32 [8192][2048], first 1024 cols) -> xb bf16 [8192][1024]
// blocks [4096,5632): Wq/Wk/Wv (fp32 [16][128][2048]) -> wb bf16 [3072][1024]
__global__ __launch_bounds__(256) void conv_all(const float* __restrict__ x,
                                                const float* __restrict__ Wq,
                                                const float* __restrict__ Wk,
                                                const float* __restrict__ Wv,
                                                unsigned short* __restrict__ xb,
                                                unsigned short* __restrict__ wb) {
  const int bid = blockIdx.x;
  const float* src;
  unsigned short* dst;
  size_t idx;
  if (bid < 4096) {
    idx = ((size_t)bid * 256 + threadIdx.x) * 8;
    const int m = (int)(idx >> 10);
    const int e = (int)(idx & 1023);
    src = x + (size_t)m * 2048 + e;
    dst = xb + idx;
  } else {
    idx = ((size_t)(bid - 4096) * 256 + threadIdx.x) * 8;
    const int n = (int)(idx >> 10);
    const int e = (int)(idx & 1023);
    const int mat = n >> 10, hh = (n >> 6) & 15, d = n & 63;
    const float* W = (mat == 0) ? Wq : ((mat == 1) ? Wk : Wv);
    src = W + ((size_t)hh * 128 + d) * 2048 + e;
    dst = wb + idx;
  }
  const float4* s = (const float4*)src;
  float4 a = s[0], b = s[1];
  u16x8 v;
  v[0]=f2bf(a.x); v[1]=f2bf(a.y); v[2]=f2bf(a.z); v[3]=f2bf(a.w);
  v[4]=f2bf(b.x); v[5]=f2bf(b.y); v[6]=f2bf(b.z); v[7]=f2bf(b.w);
  *(u16x8*)dst = v;
}

// ---- GEMM: [8192 x 1024] (xb) x [3072 x 1024]^T (wb) -> Q,K [b,h,t,64], Vt [b,h,64,t]
// BM=128 BN=128 BK=32, 256 thr (4 waves, 2x2, wave tile 64x64) using 32x32x16 MFMA:
// 8 ds_read_b128 + 8 MFMA per wave-step (half of the 16x16x32 version).
// T4 counted-vmcnt pipeline depth 2, 3 LDS buffers (48KB -> 3 blocks/CU).
// Tiles packed [32 rows][256B] (four 32-row m-segments/row), XOR (row&15)<<4
// -> 2-way conflicts only (free, m136); stage source inverse-swizzled.
__global__ __launch_bounds__(256, 3) void qkv_gemm6(const unsigned short* __restrict__ xb,
                                                    const unsigned short* __restrict__ wb,
                                                    unsigned short* __restrict__ Q,
                                                    unsigned short* __restrict__ Kt,
                                                    unsigned short* __restrict__ Vt) {
  __shared__ unsigned short As[3][32 * 128];   // 8KB/buf  (128 m x 32 k packed)
  __shared__ unsigned short Bs[3][32 * 128];   // 8KB/buf
  const int tid = threadIdx.x;
  const int w = tid >> 6, lane = tid & 63;
  const int ql = lane & 31, hi = lane >> 5;
  const int wm = w >> 1, wn = w & 1;
  const int m0 = blockIdx.x * 128;
  const int n0 = blockIdx.y * 128;

  // --- hoisted staging offsets (2 gld16 each for A and B per step, 4 loads/thread)
  size_t aoff[2], boff[2];
  int lofs[2];
#pragma unroll
  for (int it = 0; it < 2; ++it) {
    const int o = (it * 256 + tid) * 16;        // linear LDS byte 0..8191
    const int row = o >> 8, stored = o & 255;   // 32 rows x 256B
    const int logical = stored ^ ((row & 15) << 4);
    const int seg = logical >> 6, kb = logical & 63;
    const int m = row + (seg << 5);             // global m/n row in tile
    aoff[it] = ((size_t)(m0 + m) << 10) + (kb >> 1);
    boff[it] = ((size_t)(n0 + m) << 10) + (kb >> 1);
    lofs[it] = o;
  }
  // --- hoisted ds_read byte offsets [mi][kk] within an 8KB buffer
  int ardo[2][2], brdo[2][2];
#pragma unroll
  for (int mi = 0; mi < 2; ++mi)
#pragma unroll
    for (int kk = 0; kk < 2; ++kk) {
      const int m = wm * 64 + mi * 32 + ql;
      ardo[mi][kk] = (m & 31) * 256 +
                     ((((m >> 5) << 6) + kk * 32 + hi * 16) ^ ((m & 15) << 4));
      const int n = wn * 64 + mi * 32 + ql;
      brdo[mi][kk] = (n & 31) * 256 +
                     ((((n >> 5) << 6) + kk * 32 + hi * 16) ^ ((n & 15) << 4));
    }

  f32x16 acc[2][2];
#pragma unroll
  for (int mi = 0; mi < 2; ++mi)
#pragma unroll
    for (int ni = 0; ni < 2; ++ni)
#pragma unroll
      for (int r = 0; r < 16; ++r) acc[mi][ni][r] = 0.f;

  auto STAGE = [&](int k0, int buf) {
#pragma unroll
    for (int it = 0; it < 2; ++it) {
      gld16(xb + aoff[it] + k0, (char*)&As[buf][0] + lofs[it]);
      gld16(wb + boff[it] + k0, (char*)&Bs[buf][0] + lofs[it]);
    }
  };

  // prologue: tiles 0,1 in flight; tile 1's 4 loads may stay outstanding
  STAGE(0, 0);
  STAGE(32, 1);
  asm volatile("s_waitcnt vmcnt(4)" ::: "memory");
  __builtin_amdgcn_s_barrier();

  int b0 = 0, b1 = 1, b2 = 2;    // read b0; b1 in flight; stage into b2
  for (int t = 0; t < 32; ++t) {
    const bool more = (t + 2 < 32);
    if (more) STAGE((t + 2) * 32, b2);   // buffer b2 was read at iter t-1 (barrier'd)
    bf16x8 af[2][2], bf[2][2];
#pragma unroll
    for (int mi = 0; mi < 2; ++mi)
#pragma unroll
      for (int kk = 0; kk < 2; ++kk) {
        af[mi][kk] = *(const bf16x8*)((const char*)&As[b0][0] + ardo[mi][kk]);
        bf[mi][kk] = *(const bf16x8*)((const char*)&Bs[b0][0] + brdo[mi][kk]);
      }
    __builtin_amdgcn_s_setprio(1);
#pragma unroll
    for (int kk = 0; kk < 2; ++kk)
#pragma unroll
      for (int mi = 0; mi < 2; ++mi)
#pragma unroll
        for (int ni = 0; ni < 2; ++ni)
          acc[mi][ni] = __builtin_amdgcn_mfma_f32_32x32x16_bf16(af[mi][kk], bf[ni][kk],
                                                                acc[mi][ni], 0, 0, 0);
    __builtin_amdgcn_s_setprio(0);
    // t+1 must be landed before next iter reads it; t+2's 4 loads stay in flight
    if (more) asm volatile("s_waitcnt vmcnt(4)" ::: "memory");
    else      asm volatile("s_waitcnt vmcnt(0)" ::: "memory");
    __builtin_amdgcn_s_barrier();
    const int tmp = b0; b0 = b1; b1 = b2; b2 = tmp;
  }

  // epilogue: 32x32 C layout: col=lane&31, row=(r&3)+8*(r>>2)+4*hi
#pragma unroll
  for (int mi = 0; mi < 2; ++mi)
#pragma unroll
    for (int ni = 0; ni < 2; ++ni) {
      const int n = n0 + wn * 64 + ni * 32 + ql;
      const int mat = n >> 10, hh = (n >> 6) & 15, d = n & 63;
#pragma unroll
      for (int r = 0; r < 16; ++r) {
        const int row = (r & 3) + 8 * (r >> 2) + 4 * hi;
        const int m = m0 + wm * 64 + mi * 32 + row;
        const int b = m >> 11, tt = m & 2047;
        const unsigned short v = f2bf(acc[mi][ni][r]);
        const size_t bh = (size_t)(b * 16 + hh);
        if (mat == 0)      Q [(bh * TT + tt) * 64 + d] = v;
        else if (mat == 1) Kt[(bh * TT + tt) * 64 + d] = v;
        else               Vt[(bh * 64 + d) * TT + tt] = v;
      }
    }
}

// ---- flash attention, causal. 4 waves/block, 32 q-rows/wave, block shares a
// 64-k double-buffered LDS stream for K and Vt (T3 2-phase + T2 swizzle).
// Swapped layout: S^T = mfma(K, Q); lane owns q = lane&31. O^T = mfma(Vt, P^T).
// Also zeroes this (b, q-rows, h) slice of the pad columns.
__global__ __launch_bounds__(256) void attn4(const unsigned short* __restrict__ Q,
                                             const unsigned short* __restrict__ K,
                                             const unsigned short* __restrict__ Vt,
                                             float* __restrict__ out) {
  __shared__ unsigned short Ks[2][4096];   // [buf][krow*64 + d]  (swizzled), 8KB/buf
  __shared__ unsigned short Vs[2][4096];   // [buf][d*64 + t]     (swizzled), 8KB/buf
  const int blk = blockIdx.x;              // 1024 = 64 bh * 16 q-blocks
  const int bh = blk & 63;                 // bh%8 -> XCD L2 affinity
  const int qi = 15 - (blk >> 6);          // heavy (high-q) blocks first
  const int b = bh >> 4, h = bh & 15;
  const int tid = threadIdx.x;
  const int w = tid >> 6, lane = tid & 63;
  const int ql = lane & 31;
  const int hi = lane >> 5, hi8 = hi * 8;
  const int q0 = qi * 128;
  const int qw = q0 + w * 32;              // this wave's q-tile base
  const int q = qw + ql;
  const unsigned short* Qp = Q  + (size_t)bh * TT * 64;
  const unsigned short* Kp = K  + (size_t)bh * TT * 64;
  const unsigned short* Vp = Vt + (size_t)bh * 64 * TT;

  bf16x8 qf0, qf1, qf2, qf3;
  {
    const unsigned short* qa = Qp + (size_t)q * 64 + hi8;
    qf0 = *(const bf16x8*)(qa);
    qf1 = *(const bf16x8*)(qa + 16);
    qf2 = *(const bf16x8*)(qa + 32);
    qf3 = *(const bf16x8*)(qa + 48);
  }

  f32x16 o0, o1;
#pragma unroll
  for (int r = 0; r < 16; ++r) { o0[r] = 0.f; o1[r] = 0.f; }
  float m = -3.0e38f, l = 0.f;
  const float c2 = 0.125f * 1.44269504f;

  const int nt = qi * 2 + 2;               // 64-k tiles covering [0, q0+128)

  auto STAGE = [&](int t, int buf) {
#pragma unroll
    for (int it = 0; it < 2; ++it) {
      const int o = (it * 256 + tid) * 16;       // byte offset 0..8191
      const int r = o >> 7, c = o & 127;
      const int cs = c ^ ((r & 7) << 4);
      gld16(Kp + (size_t)t * 4096 + r * 64 + (cs >> 1), (char*)&Ks[buf][0] + o);
      gld16(Vp + (size_t)r * 2048 + t * 64 + (cs >> 1), (char*)&Vs[buf][0] + o);
    }
  };

  STAGE(0, 0);
  asm volatile("s_waitcnt vmcnt(0)" ::: "memory");
  __syncthreads();

  int cur = 0;
  for (int t = 0; t < nt; ++t) {
    if (t + 1 < nt) STAGE(t + 1, cur ^ 1);

#pragma unroll
    for (int s = 0; s < 2; ++s) {
      const int ks32 = t * 64 + s * 32;
      if (ks32 <= qw) {
        // --- K fragments from LDS (A operand: rows = k, 8 d-elems per frag)
        const int krow = s * 32 + ql;
        const char* kb = (const char*)&Ks[cur][krow * 64];
        const int ksz = (krow & 7) << 4;
        bf16x8 kf0 = *(const bf16x8*)(kb + ((0  + hi * 16) ^ ksz));
        bf16x8 kf1 = *(const bf16x8*)(kb + ((32 + hi * 16) ^ ksz));
        bf16x8 kf2 = *(const bf16x8*)(kb + ((64 + hi * 16) ^ ksz));
        bf16x8 kf3 = *(const bf16x8*)(kb + ((96 + hi * 16) ^ ksz));
        // --- V fragments from LDS (A operand: rows = d, 8 t-elems per frag)
        const int vsz = (ql & 7) << 4;
        const char* vb0 = (const char*)&Vs[cur][ql * 64];
        const char* vb1 = (const char*)&Vs[cur][(ql + 32) * 64];
        bf16x8 vf0 = *(const bf16x8*)(vb0 + ((s * 64 + 0  + hi * 16) ^ vsz));
        bf16x8 vf1 = *(const bf16x8*)(vb0 + ((s * 64 + 32 + hi * 16) ^ vsz));
        bf16x8 vf2 = *(const bf16x8*)(vb1 + ((s * 64 + 0  + hi * 16) ^ vsz));
        bf16x8 vf3 = *(const bf16x8*)(vb1 + ((s * 64 + 32 + hi * 16) ^ vsz));

        // --- QK^T swapped: st[r] = S^T[k=(r&3)+8*(r>>2)+4*hi][q=ql]
        f32x16 st;
#pragma unroll
        for (int r = 0; r < 16; ++r) st[r] = 0.f;
        __builtin_amdgcn_s_setprio(1);
        st = __builtin_amdgcn_mfma_f32_32x32x16_bf16(kf0, qf0, st, 0, 0, 0);
        st = __builtin_amdgcn_mfma_f32_32x32x16_bf16(kf1, qf1, st, 0, 0, 0);
        st = __builtin_amdgcn_mfma_f32_32x32x16_bf16(kf2, qf2, st, 0, 0, 0);
        st = __builtin_amdgcn_mfma_f32_32x32x16_bf16(kf3, qf3, st, 0, 0, 0);
        __builtin_amdgcn_s_setprio(0);

        if (ks32 == qw) {                  // diagonal sub-tile: causal mask
#pragma unroll
          for (int r = 0; r < 16; ++r) {
            const int krw = (r & 3) + 8 * (r >> 2) + 4 * hi;
            if (krw > ql) st[r] = -3.0e38f;
          }
        }

        // --- online softmax, in-register (lane owns q=ql)
        float t0 = fmaxf(st[0], st[1]),  t1 = fmaxf(st[2], st[3]);
        float t2 = fmaxf(st[4], st[5]),  t3 = fmaxf(st[6], st[7]);
        float t4 = fmaxf(st[8], st[9]),  t5 = fmaxf(st[10], st[11]);
        float t6 = fmaxf(st[12], st[13]), t7 = fmaxf(st[14], st[15]);
        t0 = fmaxf(t0, t1); t2 = fmaxf(t2, t3); t4 = fmaxf(t4, t5); t6 = fmaxf(t6, t7);
        float pm = fmaxf(fmaxf(t0, t2), fmaxf(t4, t6));
        pm = fmaxf(pm, __shfl_xor(pm, 32));
        if (!__all(pm - m <= 44.36f)) {    // defer-max (THR=8 in exp units)
          const float mnew = fmaxf(m, pm);
          const float alpha = __builtin_amdgcn_exp2f((m - mnew) * c2);
          m = mnew;
          l *= alpha;
#pragma unroll
          for (int r = 0; r < 16; ++r) { o0[r] *= alpha; o1[r] *= alpha; }
        }
        float p[16];
        float rs = 0.f;
#pragma unroll
        for (int r = 0; r < 16; ++r) {
          p[r] = __builtin_amdgcn_exp2f((st[r] - m) * c2);
          rs += p[r];
        }
        rs += __shfl_xor(rs, 32);
        l += rs;

        // --- pack P^T into B-fragments (cvt_pk + permlane32_swap)
        unsigned int a0 = cvtpk(p[0], p[1]),  a1 = cvtpk(p[2], p[3]);
        unsigned int b0 = cvtpk(p[4], p[5]),  b1 = cvtpk(p[6], p[7]);
        pl32swap(a0, b0); pl32swap(a1, b1);
        unsigned int cc0 = cvtpk(p[8], p[9]),  cc1 = cvtpk(p[10], p[11]);
        unsigned int dd0 = cvtpk(p[12], p[13]), dd1 = cvtpk(p[14], p[15]);
        pl32swap(cc0, dd0); pl32swap(cc1, dd1);
        u32x4 pw0 = {a0, a1, b0, b1};
        u32x4 pw1 = {cc0, cc1, dd0, dd1};
        bf16x8 pf0 = __builtin_bit_cast(bf16x8, pw0);
        bf16x8 pf1 = __builtin_bit_cast(bf16x8, pw1);

        // --- PV swapped: O^T[d][q] += V^T[d][k] * P^T[k][q]
        __builtin_amdgcn_s_setprio(1);
        o0 = __builtin_amdgcn_mfma_f32_32x32x16_bf16(vf0, pf0, o0, 0, 0, 0);
        o0 = __builtin_amdgcn_mfma_f32_32x32x16_bf16(vf1, pf1, o0, 0, 0, 0);
        o1 = __builtin_amdgcn_mfma_f32_32x32x16_bf16(vf2, pf0, o1, 0, 0, 0);
        o1 = __builtin_amdgcn_mfma_f32_32x32x16_bf16(vf3, pf1, o1, 0, 0, 0);
        __builtin_amdgcn_s_setprio(0);
      }
    }

    asm volatile("s_waitcnt vmcnt(0)" ::: "memory");
    __syncthreads();
    cur ^= 1;
  }

  const float inv = 1.f / l;
  float* ob = out + ((size_t)b * TT + q) * 2048 + h * 64;
#pragma unroll
  for (int r = 0; r < 16; ++r) {
    const int row = (r & 3) + 8 * (r >> 2) + 4 * hi;
    ob[row]      = o0[r] * inv;
    ob[32 + row] = o1[r] * inv;
  }

  // zero the pad slice: rows q0..q0+127, cols 1024+h*64 .. +63
  const float4 z = make_float4(0.f, 0.f, 0.f, 0.f);
#pragma unroll
  for (int it = 0; it < 8; ++it) {
    const int idx = it * 256 + tid;      // 0..2047
    const int r = idx >> 4, c4 = idx & 15;
    *((float4*)(out + ((size_t)b * TT + q0 + r) * 2048 + 1024 + h * 64) + c4) = z;
  }
}

extern "C" void kernel_launch(void* const* d_in, const int* in_sizes, int n_in,
                              void* d_out, int out_size, void* d_ws, size_t ws_size,
                              hipStream_t stream) {
  const float* x  = (const float*)d_in[0];
  const float* Wq = (const float*)d_in[1];
  const float* Wk = (const float*)d_in[2];
  const float* Wv = (const float*)d_in[3];

  unsigned short* wsp = (unsigned short*)d_ws;
  unsigned short* Q   = wsp;                       // 8,388,608 bf16
  unsigned short* Kt  = wsp + (size_t)8388608;
  unsigned short* Vt  = wsp + (size_t)16777216;

  // d_out doubles as scratch for bf16-converted inputs; fully overwritten later.
  unsigned short* xb = (unsigned short*)d_out;                          // 16.8 MB
  unsigned short* wb = (unsigned short*)((char*)d_out + 33554432);      // 6.3 MB
  float* out = (float*)d_out;

  conv_all<<<5632, 256, 0, stream>>>(x, Wq, Wk, Wv, xb, wb);
  qkv_gemm6<<<dim3(64, 24), 256, 0, stream>>>(xb, wb, Q, Kt, Vt);
  attn4<<<1024, 256, 0, stream>>>(Q, Kt, Vt, out);
}

// Round 10
// 164.064 us; speedup vs baseline: 1.0441x; 1.0441x over previous
//
#include <hip/hip_runtime.h>

typedef __attribute__((ext_vector_type(8))) short bf16x8;
typedef __attribute__((ext_vector_type(4))) float f32x4;
typedef __attribute__((ext_vector_type(16))) float f32x16;
typedef __attribute__((ext_vector_type(8))) unsigned short u16x8;
typedef __attribute__((ext_vector_type(4))) unsigned int u32x4;

#define TT 2048

__device__ __forceinline__ unsigned short f2bf(float f) {
  unsigned int u = __builtin_bit_cast(unsigned int, f);
  u += 0x7FFFu + ((u >> 16) & 1u);
  return (unsigned short)(u >> 16);
}

__device__ __forceinline__ void gld16(const void* g, void* l) {
  __builtin_amdgcn_global_load_lds((const __attribute__((address_space(1))) void*)g,
                                   (__attribute__((address_space(3))) void*)l, 16, 0, 0);
}

__device__ __forceinline__ unsigned int cvtpk(float lo, float hi) {
  unsigned int r;
  asm("v_cvt_pk_bf16_f32 %0, %1, %2" : "=v"(r) : "v"(lo), "v"(hi));
  return r;
}

__device__ __forceinline__ void pl32swap(unsigned int& a, unsigned int& b) {
  asm volatile("v_permlane32_swap_b32 %0, %1" : "+v"(a), "+v"(b));
}

// ---- fused input conversion:
// blocks [0,4096): x (fp32 [8192][2048], first 1024 cols) -> xb bf16 [8192][1024]
// blocks [4096,5632): Wq/Wk/Wv (fp32 [16][128][2048]) -> wb bf16 [3072][1024]
__global__ __launch_bounds__(256) void conv_all(const float* __restrict__ x,
                                                const float* __restrict__ Wq,
                                                const float* __restrict__ Wk,
                                                const float* __restrict__ Wv,
                                                unsigned short* __restrict__ xb,
                                                unsigned short* __restrict__ wb) {
  const int bid = blockIdx.x;
  const float* src;
  unsigned short* dst;
  size_t idx;
  if (bid < 4096) {
    idx = ((size_t)bid * 256 + threadIdx.x) * 8;
    const int m = (int)(idx >> 10);
    const int e = (int)(idx & 1023);
    src = x + (size_t)m * 2048 + e;
    dst = xb + idx;
  } else {
    idx = ((size_t)(bid - 4096) * 256 + threadIdx.x) * 8;
    const int n = (int)(idx >> 10);
    const int e = (int)(idx & 1023);
    const int mat = n >> 10, hh = (n >> 6) & 15, d = n & 63;
    const float* W = (mat == 0) ? Wq : ((mat == 1) ? Wk : Wv);
    src = W + ((size_t)hh * 128 + d) * 2048 + e;
    dst = wb + idx;
  }
  const float4* s = (const float4*)src;
  float4 a = s[0], b = s[1];
  u16x8 v;
  v[0]=f2bf(a.x); v[1]=f2bf(a.y); v[2]=f2bf(a.z); v[3]=f2bf(a.w);
  v[4]=f2bf(b.x); v[5]=f2bf(b.y); v[6]=f2bf(b.z); v[7]=f2bf(b.w);
  *(u16x8*)dst = v;
}

// ---- GEMM: [8192 x 1024] (xb) x [3072 x 1024]^T (wb) -> Q,K [b,h,t,64], Vt [b,h,64,t]
// BM=256 BN=128 BK=32, 256 thr (4 waves, 2Mx2N -> wave tile 128x64).
// Per wave-step: 12 ds_read_b128 + 32 MFMA (23 B/kFLOP LDS traffic, was 61).
// R8's proven skeleton: 3 LDS buffers (72KB -> 2 blocks/CU), depth-2 counted
// vmcnt(6), ONE s_barrier per step. A packed [128 rows][128B] (2 m-segments),
// B packed [64 rows][128B]; XOR (row&7)<<4 swizzle, inverse-swizzled source.
__global__ __launch_bounds__(256, 2) void qkv_gemm7(const unsigned short* __restrict__ xb,
                                                    const unsigned short* __restrict__ wb,
                                                    unsigned short* __restrict__ Q,
                                                    unsigned short* __restrict__ Kt,
                                                    unsigned short* __restrict__ Vt) {
  __shared__ unsigned short As[3][128 * 64];   // 16KB/buf (256 m x 32 k packed)
  __shared__ unsigned short Bs[3][64 * 64];    // 8KB/buf  (128 n x 32 k packed)
  const int tid = threadIdx.x;
  const int w = tid >> 6, lane = tid & 63, g = lane >> 4, c = lane & 15;
  const int wm = w >> 1, wn = w & 1;
  const int m0 = blockIdx.x * 256;
  const int n0 = blockIdx.y * 128;

  // --- hoisted staging offsets: A 4 gld16, B 2 gld16 per thread per tile
  size_t aoff[4], boff[2];
  int alofs[4], blofs[2];
#pragma unroll
  for (int it = 0; it < 4; ++it) {
    const int o = (it * 256 + tid) * 16;        // [0,16384)
    const int row = o >> 7, stored = o & 127;
    const int logical = stored ^ ((row & 7) << 4);
    const int seg = logical >> 6, kb = logical & 63;
    const int m = row + (seg << 7);             // 2 segments of 128 rows
    aoff[it] = ((size_t)(m0 + m) << 10) + (kb >> 1);
    alofs[it] = o;
  }
#pragma unroll
  for (int it = 0; it < 2; ++it) {
    const int o = (it * 256 + tid) * 16;        // [0,8192)
    const int row = o >> 7, stored = o & 127;
    const int logical = stored ^ ((row & 7) << 4);
    const int seg = logical >> 6, kb = logical & 63;
    const int n = row + (seg << 6);             // 2 segments of 64 rows
    boff[it] = ((size_t)(n0 + n) << 10) + (kb >> 1);
    blofs[it] = o;
  }
  // --- hoisted ds_read byte offsets
  int ardo[8], brdo[4];
#pragma unroll
  for (int mi = 0; mi < 8; ++mi) {
    const int m = wm * 128 + mi * 16 + c;
    const int row = m & 127, seg = m >> 7;
    ardo[mi] = row * 128 + (((seg << 6) + (g << 4)) ^ ((row & 7) << 4));
  }
#pragma unroll
  for (int ni = 0; ni < 4; ++ni) {
    const int n = wn * 64 + ni * 16 + c;
    const int row = n & 63, seg = n >> 6;
    brdo[ni] = row * 128 + (((seg << 6) + (g << 4)) ^ ((row & 7) << 4));
  }

  f32x4 acc[8][4];
#pragma unroll
  for (int mi = 0; mi < 8; ++mi)
#pragma unroll
    for (int ni = 0; ni < 4; ++ni) acc[mi][ni] = (f32x4){0.f, 0.f, 0.f, 0.f};

  auto STAGE = [&](int k0, int buf) {
#pragma unroll
    for (int it = 0; it < 4; ++it)
      gld16(xb + aoff[it] + k0, (char*)&As[buf][0] + alofs[it]);
#pragma unroll
    for (int it = 0; it < 2; ++it)
      gld16(wb + boff[it] + k0, (char*)&Bs[buf][0] + blofs[it]);
  };

  // prologue: tiles 0,1 in flight; tile 1's 6 loads may stay outstanding
  STAGE(0, 0);
  STAGE(32, 1);
  asm volatile("s_waitcnt vmcnt(6)" ::: "memory");
  __builtin_amdgcn_s_barrier();

  int b0 = 0, b1 = 1, b2 = 2;    // read b0; b1 in flight; stage into b2
  for (int t = 0; t < 32; ++t) {
    const bool more = (t + 2 < 32);
    if (more) STAGE((t + 2) * 32, b2);   // b2 was read at iter t-1 (barrier'd)
    bf16x8 af[8], bfv[4];
#pragma unroll
    for (int mi = 0; mi < 8; ++mi)
      af[mi] = *(const bf16x8*)((const char*)&As[b0][0] + ardo[mi]);
#pragma unroll
    for (int ni = 0; ni < 4; ++ni)
      bfv[ni] = *(const bf16x8*)((const char*)&Bs[b0][0] + brdo[ni]);
    __builtin_amdgcn_s_setprio(1);
#pragma unroll
    for (int mi = 0; mi < 8; ++mi)
#pragma unroll
      for (int ni = 0; ni < 4; ++ni)
        acc[mi][ni] = __builtin_amdgcn_mfma_f32_16x16x32_bf16(af[mi], bfv[ni], acc[mi][ni], 0, 0, 0);
    __builtin_amdgcn_s_setprio(0);
    // t+1 landed before next iter reads it; t+2's 6 loads stay in flight (T4)
    if (more) asm volatile("s_waitcnt vmcnt(6)" ::: "memory");
    else      asm volatile("s_waitcnt vmcnt(0)" ::: "memory");
    __builtin_amdgcn_s_barrier();
    const int tmp = b0; b0 = b1; b1 = b2; b2 = tmp;
  }

  // epilogue: C[row=(lane>>4)*4+i, col=lane&15]
#pragma unroll
  for (int mi = 0; mi < 8; ++mi) {
    const int row_l = wm * 128 + mi * 16 + g * 4;
#pragma unroll
    for (int i = 0; i < 4; ++i) {
      const int m = m0 + row_l + i;
      const int b = m >> 11, tt = m & 2047;
#pragma unroll
      for (int ni = 0; ni < 4; ++ni) {
        const int n = n0 + wn * 64 + ni * 16 + c;
        const int mat = n >> 10, hh = (n >> 6) & 15, d = n & 63;
        const unsigned short v = f2bf(acc[mi][ni][i]);
        const size_t bh = (size_t)(b * 16 + hh);
        if (mat == 0)      Q [(bh * TT + tt) * 64 + d] = v;
        else if (mat == 1) Kt[(bh * TT + tt) * 64 + d] = v;
        else               Vt[(bh * 64 + d) * TT + tt] = v;
      }
    }
  }
}

// ---- flash attention, causal. 4 waves/block, 32 q-rows/wave, block shares a
// 64-k double-buffered LDS stream for K and Vt (T3 2-phase + T2 swizzle).
// Swapped layout: S^T = mfma(K, Q); lane owns q = lane&31. O^T = mfma(Vt, P^T).
// Also zeroes this (b, q-rows, h) slice of the pad columns.
__global__ __launch_bounds__(256) void attn4(const unsigned short* __restrict__ Q,
                                             const unsigned short* __restrict__ K,
                                             const unsigned short* __restrict__ Vt,
                                             float* __restrict__ out) {
  __shared__ unsigned short Ks[2][4096];   // [buf][krow*64 + d]  (swizzled), 8KB/buf
  __shared__ unsigned short Vs[2][4096];   // [buf][d*64 + t]     (swizzled), 8KB/buf
  const int blk = blockIdx.x;              // 1024 = 64 bh * 16 q-blocks
  const int bh = blk & 63;                 // bh%8 -> XCD L2 affinity
  const int qi = 15 - (blk >> 6);          // heavy (high-q) blocks first
  const int b = bh >> 4, h = bh & 15;
  const int tid = threadIdx.x;
  const int w = tid >> 6, lane = tid & 63;
  const int ql = lane & 31;
  const int hi = lane >> 5, hi8 = hi * 8;
  const int q0 = qi * 128;
  const int qw = q0 + w * 32;              // this wave's q-tile base
  const int q = qw + ql;
  const unsigned short* Qp = Q  + (size_t)bh * TT * 64;
  const unsigned short* Kp = K  + (size_t)bh * TT * 64;
  const unsigned short* Vp = Vt + (size_t)bh * 64 * TT;

  bf16x8 qf0, qf1, qf2, qf3;
  {
    const unsigned short* qa = Qp + (size_t)q * 64 + hi8;
    qf0 = *(const bf16x8*)(qa);
    qf1 = *(const bf16x8*)(qa + 16);
    qf2 = *(const bf16x8*)(qa + 32);
    qf3 = *(const bf16x8*)(qa + 48);
  }

  f32x16 o0, o1;
#pragma unroll
  for (int r = 0; r < 16; ++r) { o0[r] = 0.f; o1[r] = 0.f; }
  float m = -3.0e38f, l = 0.f;
  const float c2 = 0.125f * 1.44269504f;

  const int nt = qi * 2 + 2;               // 64-k tiles covering [0, q0+128)

  auto STAGE = [&](int t, int buf) {
#pragma unroll
    for (int it = 0; it < 2; ++it) {
      const int o = (it * 256 + tid) * 16;       // byte offset 0..8191
      const int r = o >> 7, c = o & 127;
      const int cs = c ^ ((r & 7) << 4);
      gld16(Kp + (size_t)t * 4096 + r * 64 + (cs >> 1), (char*)&Ks[buf][0] + o);
      gld16(Vp + (size_t)r * 2048 + t * 64 + (cs >> 1), (char*)&Vs[buf][0] + o);
    }
  };

  STAGE(0, 0);
  asm volatile("s_waitcnt vmcnt(0)" ::: "memory");
  __syncthreads();

  int cur = 0;
  for (int t = 0; t < nt; ++t) {
    if (t + 1 < nt) STAGE(t + 1, cur ^ 1);

#pragma unroll
    for (int s = 0; s < 2; ++s) {
      const int ks32 = t * 64 + s * 32;
      if (ks32 <= qw) {
        // --- K fragments from LDS (A operand: rows = k, 8 d-elems per frag)
        const int krow = s * 32 + ql;
        const char* kb = (const char*)&Ks[cur][krow * 64];
        const int ksz = (krow & 7) << 4;
        bf16x8 kf0 = *(const bf16x8*)(kb + ((0  + hi * 16) ^ ksz));
        bf16x8 kf1 = *(const bf16x8*)(kb + ((32 + hi * 16) ^ ksz));
        bf16x8 kf2 = *(const bf16x8*)(kb + ((64 + hi * 16) ^ ksz));
        bf16x8 kf3 = *(const bf16x8*)(kb + ((96 + hi * 16) ^ ksz));
        // --- V fragments from LDS (A operand: rows = d, 8 t-elems per frag)
        const int vsz = (ql & 7) << 4;
        const char* vb0 = (const char*)&Vs[cur][ql * 64];
        const char* vb1 = (const char*)&Vs[cur][(ql + 32) * 64];
        bf16x8 vf0 = *(const bf16x8*)(vb0 + ((s * 64 + 0  + hi * 16) ^ vsz));
        bf16x8 vf1 = *(const bf16x8*)(vb0 + ((s * 64 + 32 + hi * 16) ^ vsz));
        bf16x8 vf2 = *(const bf16x8*)(vb1 + ((s * 64 + 0  + hi * 16) ^ vsz));
        bf16x8 vf3 = *(const bf16x8*)(vb1 + ((s * 64 + 32 + hi * 16) ^ vsz));

        // --- QK^T swapped: st[r] = S^T[k=(r&3)+8*(r>>2)+4*hi][q=ql]
        f32x16 st;
#pragma unroll
        for (int r = 0; r < 16; ++r) st[r] = 0.f;
        __builtin_amdgcn_s_setprio(1);
        st = __builtin_amdgcn_mfma_f32_32x32x16_bf16(kf0, qf0, st, 0, 0, 0);
        st = __builtin_amdgcn_mfma_f32_32x32x16_bf16(kf1, qf1, st, 0, 0, 0);
        st = __builtin_amdgcn_mfma_f32_32x32x16_bf16(kf2, qf2, st, 0, 0, 0);
        st = __builtin_amdgcn_mfma_f32_32x32x16_bf16(kf3, qf3, st, 0, 0, 0);
        __builtin_amdgcn_s_setprio(0);

        if (ks32 == qw) {                  // diagonal sub-tile: causal mask
#pragma unroll
          for (int r = 0; r < 16; ++r) {
            const int krw = (r & 3) + 8 * (r >> 2) + 4 * hi;
            if (krw > ql) st[r] = -3.0e38f;
          }
        }

        // --- online softmax, in-register (lane owns q=ql)
        float t0 = fmaxf(st[0], st[1]),  t1 = fmaxf(st[2], st[3]);
        float t2 = fmaxf(st[4], st[5]),  t3 = fmaxf(st[6], st[7]);
        float t4 = fmaxf(st[8], st[9]),  t5 = fmaxf(st[10], st[11]);
        float t6 = fmaxf(st[12], st[13]), t7 = fmaxf(st[14], st[15]);
        t0 = fmaxf(t0, t1); t2 = fmaxf(t2, t3); t4 = fmaxf(t4, t5); t6 = fmaxf(t6, t7);
        float pm = fmaxf(fmaxf(t0, t2), fmaxf(t4, t6));
        pm = fmaxf(pm, __shfl_xor(pm, 32));
        if (!__all(pm - m <= 44.36f)) {    // defer-max (THR=8 in exp units)
          const float mnew = fmaxf(m, pm);
          const float alpha = __builtin_amdgcn_exp2f((m - mnew) * c2);
          m = mnew;
          l *= alpha;
#pragma unroll
          for (int r = 0; r < 16; ++r) { o0[r] *= alpha; o1[r] *= alpha; }
        }
        float p[16];
        float rs = 0.f;
#pragma unroll
        for (int r = 0; r < 16; ++r) {
          p[r] = __builtin_amdgcn_exp2f((st[r] - m) * c2);
          rs += p[r];
        }
        rs += __shfl_xor(rs, 32);
        l += rs;

        // --- pack P^T into B-fragments (cvt_pk + permlane32_swap)
        unsigned int a0 = cvtpk(p[0], p[1]),  a1 = cvtpk(p[2], p[3]);
        unsigned int b0 = cvtpk(p[4], p[5]),  b1 = cvtpk(p[6], p[7]);
        pl32swap(a0, b0); pl32swap(a1, b1);
        unsigned int cc0 = cvtpk(p[8], p[9]),  cc1 = cvtpk(p[10], p[11]);
        unsigned int dd0 = cvtpk(p[12], p[13]), dd1 = cvtpk(p[14], p[15]);
        pl32swap(cc0, dd0); pl32swap(cc1, dd1);
        u32x4 pw0 = {a0, a1, b0, b1};
        u32x4 pw1 = {cc0, cc1, dd0, dd1};
        bf16x8 pf0 = __builtin_bit_cast(bf16x8, pw0);
        bf16x8 pf1 = __builtin_bit_cast(bf16x8, pw1);

        // --- PV swapped: O^T[d][q] += V^T[d][k] * P^T[k][q]
        __builtin_amdgcn_s_setprio(1);
        o0 = __builtin_amdgcn_mfma_f32_32x32x16_bf16(vf0, pf0, o0, 0, 0, 0);
        o0 = __builtin_amdgcn_mfma_f32_32x32x16_bf16(vf1, pf1, o0, 0, 0, 0);
        o1 = __builtin_amdgcn_mfma_f32_32x32x16_bf16(vf2, pf0, o1, 0, 0, 0);
        o1 = __builtin_amdgcn_mfma_f32_32x32x16_bf16(vf3, pf1, o1, 0, 0, 0);
        __builtin_amdgcn_s_setprio(0);
      }
    }

    asm volatile("s_waitcnt vmcnt(0)" ::: "memory");
    __syncthreads();
    cur ^= 1;
  }

  const float inv = 1.f / l;
  float* ob = out + ((size_t)b * TT + q) * 2048 + h * 64;
#pragma unroll
  for (int r = 0; r < 16; ++r) {
    const int row = (r & 3) + 8 * (r >> 2) + 4 * hi;
    ob[row]      = o0[r] * inv;
    ob[32 + row] = o1[r] * inv;
  }

  // zero the pad slice: rows q0..q0+127, cols 1024+h*64 .. +63
  const float4 z = make_float4(0.f, 0.f, 0.f, 0.f);
#pragma unroll
  for (int it = 0; it < 8; ++it) {
    const int idx = it * 256 + tid;      // 0..2047
    const int r = idx >> 4, c4 = idx & 15;
    *((float4*)(out + ((size_t)b * TT + q0 + r) * 2048 + 1024 + h * 64) + c4) = z;
  }
}

extern "C" void kernel_launch(void* const* d_in, const int* in_sizes, int n_in,
                              void* d_out, int out_size, void* d_ws, size_t ws_size,
                              hipStream_t stream) {
  const float* x  = (const float*)d_in[0];
  const float* Wq = (const float*)d_in[1];
  const float* Wk = (const float*)d_in[2];
  const float* Wv = (const float*)d_in[3];

  unsigned short* wsp = (unsigned short*)d_ws;
  unsigned short* Q   = wsp;                       // 8,388,608 bf16
  unsigned short* Kt  = wsp + (size_t)8388608;
  unsigned short* Vt  = wsp + (size_t)16777216;

  // d_out doubles as scratch for bf16-converted inputs; fully overwritten later.
  unsigned short* xb = (unsigned short*)d_out;                          // 16.8 MB
  unsigned short* wb = (unsigned short*)((char*)d_out + 33554432);      // 6.3 MB
  float* out = (float*)d_out;

  conv_all<<<5632, 256, 0, stream>>>(x, Wq, Wk, Wv, xb, wb);
  qkv_gemm7<<<dim3(32, 24), 256, 0, stream>>>(xb, wb, Q, Kt, Vt);
  attn4<<<1024, 256, 0, stream>>>(Q, Kt, Vt, out);
}